// Round 11
// baseline (4284.979 us; speedup 1.0000x reference)
//
#include <hip/hip_runtime.h>
#include <cstddef>

#define NN 256      // N
#define PP 256      // P
#define BB 128      // B
#define KK 4        // K
#define NSYS 512    // K*B
#define PW 32       // panel width
#define NPAN (NN/PW)

__device__ __forceinline__ float sigmoidf_(float x){ return 1.0f/(1.0f+expf(-x)); }

// ---------------------------------------------------------------------------
// Kernel 1: build Cm (A) and rowsum(Cm) for systems [s0,s0+cs)
// ---------------------------------------------------------------------------
__global__ __launch_bounds__(256) void build_kernel(
    const float* __restrict__ C, const float* __restrict__ rm,
    const float* __restrict__ epsp, const int* __restrict__ bad,
    float* __restrict__ A, float* __restrict__ rowsum, int s0)
{
  const int si = blockIdx.x;
  const int ls = si >> 8;
  const int i  = si & 255;
  const int s  = s0 + ls;
  const int k  = s >> 7;
  const int b  = s & 127;
  const int j  = threadIdx.x;

  const float sk = sigmoidf_(rm[k]);
  const float ek = sigmoidf_(epsp[k]);
  const bool bad_i = bad[b*NN + i] != 0;
  const bool bad_j = bad[b*NN + j] != 0;

  float c  = C[((size_t)b*NN + i)*(NN+PP) + j];
  float x  = sk * c;
  float cf = (1.0f + x) * expf(-x);
  if (i == j) cf += ek;              // diag: C[i][i]==0 -> cf==1, add eps
  float keep = (bad_i == bad_j) ? 1.0f : 0.0f;
  float a = cf * keep;
  A[((size_t)ls*NN + i)*NN + j] = a;

  __shared__ float red[256];
  red[j] = a; __syncthreads();
  #pragma unroll
  for (int off = 128; off > 0; off >>= 1){
    if (j < off) red[j] += red[j + off];
    __syncthreads();
  }
  if (j == 0) rowsum[ls*NN + i] = red[0];
}

// ---------------------------------------------------------------------------
// Kernel 2: swap-free blocked LU with partial pivoting ("pick-order").
// (round-8 version — measured good: no spill, ~650 us)
// ---------------------------------------------------------------------------
__global__ __launch_bounds__(512, 4) void lu_kernel(
    float* __restrict__ Aall, int* __restrict__ permAll)
{
  __shared__ float panel[NN][PW+1];
  __shared__ float linv[PW][PW+1];
  __shared__ float uinv[PW][PW+1];
  __shared__ float urow[PW][NN-PW];
  __shared__ float redv[2][8];
  __shared__ int   redi[2][8];
  __shared__ int   pivseq[NN];
  __shared__ int   actlist[NN];
  __shared__ unsigned char pickedsh[NN];
  __shared__ int   nact;

  const int ls = blockIdx.x;
  float* __restrict__ A = Aall + (size_t)ls*NN*NN;
  const int t = threadIdx.x;
  const int lane = t & 63, wid = t >> 6;
  bool picked = false;
  if (t < NN) pickedsh[t] = 0;

  for (int I = 0; I < NPAN; ++I){
    const int col0 = I*PW;
    const int W = NN - col0 - PW;
    if (t == 0) nact = 0;
    __syncthreads();

    for (int e = t; e < NN*PW; e += 512){
      int r = e >> 5, c = e & 31;
      panel[r][c] = A[(size_t)r*NN + col0 + c];
    }
    __syncthreads();

    {
      float v = -1.0f; int vi = 0;
      if (t < NN && !picked){ v = fabsf(panel[t][0]); vi = t; }
      #pragma unroll
      for (int off = 32; off > 0; off >>= 1){
        float ov = __shfl_down(v, off); int oi = __shfl_down(vi, off);
        if (ov > v){ v = ov; vi = oi; }
      }
      if (lane == 0){ redv[0][wid] = v; redi[0][wid] = vi; }
    }
    __syncthreads();

    for (int c = 0; c < PW; ++c){
      const int par = c & 1;
      float bv = redv[par][0]; int p = redi[par][0];
      #pragma unroll
      for (int w = 1; w < 8; ++w)
        if (redv[par][w] > bv){ bv = redv[par][w]; p = redi[par][w]; }
      if (t == p){ picked = true; pickedsh[t] = 1; pivseq[col0+c] = t; }

      float nv = -1.0f; int ni = t;
      if (t < NN && !picked){
        const float rdia = 1.0f / panel[p][c];
        float m = panel[t][c] * rdia;
        panel[t][c] = m;
        float nxt = -1.0f;
        #pragma unroll
        for (int j = 0; j < PW; ++j){
          if (j > c){
            float u = panel[t][j] - m * panel[p][j];
            panel[t][j] = u;
            if (j == c+1) nxt = fabsf(u);
          }
        }
        nv = nxt;
      }
      #pragma unroll
      for (int off = 32; off > 0; off >>= 1){
        float ov = __shfl_down(nv, off); int oi = __shfl_down(ni, off);
        if (ov > nv){ nv = ov; ni = oi; }
      }
      if (lane == 0){ redv[par^1][wid] = nv; redi[par^1][wid] = ni; }
      __syncthreads();
    }

    if (t >= 256){
      const int jj = t - 256;
      if (jj < W){
        const int j = col0 + PW + jj;
        float u[PW];
        #pragma unroll
        for (int c = 0; c < PW; ++c) u[c] = A[(size_t)pivseq[col0+c]*NN + j];
        #pragma unroll
        for (int c = 0; c < PW; ++c){
          const int pc = pivseq[col0+c];
          float sv = u[c];
          #pragma unroll
          for (int k2 = 0; k2 < PW; ++k2)
            if (k2 < c) sv -= panel[pc][k2] * u[k2];
          u[c] = sv;
          urow[c][jj] = sv;
          A[(size_t)pc*NN + j] = sv;
        }
      }
    } else if (t < PW){
      const int cth = t;
      for (int r = cth; r < PW; ++r){
        float sv = (r == cth) ? 1.0f : 0.0f;
        const int pr = pivseq[col0+r];
        for (int k2 = cth; k2 < r; ++k2) sv -= panel[pr][k2] * linv[k2][cth];
        linv[r][cth] = sv;
      }
    } else if (t >= 64 && t < 64+PW){
      const int cth = t - 64;
      for (int r = cth; r >= 0; --r){
        float sv = (r == cth) ? 1.0f : 0.0f;
        const int pr = pivseq[col0+r];
        for (int k2 = r+1; k2 <= cth; ++k2) sv -= panel[pr][k2] * uinv[k2][cth];
        uinv[r][cth] = sv / panel[pr][r];
      }
    } else if (t >= 128 && t < 192){
      #pragma unroll
      for (int q = 0; q < 4; ++q){
        int r = (t-128)*4 + q;
        if (!pickedsh[r]){ int pos = atomicAdd(&nact, 1); actlist[pos] = r; }
      }
    }
    __syncthreads();

    for (int e = t; e < PW*PW; e += 512){
      int r = e >> 5, c2 = e & 31;
      A[(size_t)pivseq[col0+r]*NN + col0 + c2] = (r > c2) ? linv[r][c2] : uinv[r][c2];
    }
    for (int e = t; e < NN*PW; e += 512){
      int r = e >> 5, c2 = e & 31;
      if (!pickedsh[r]) A[(size_t)r*NN + col0 + c2] = panel[r][c2];
    }

    if (W > 0){
      for (int i0 = wid*2; i0 < W; i0 += 16){
        const int r0 = actlist[i0];
        const int r1 = actlist[i0+1];          // W even: pair valid
        float4* R0 = (float4*)(A + (size_t)r0*NN + col0 + PW);
        float4* R1 = (float4*)(A + (size_t)r1*NN + col0 + PW);
        if (lane*4 < W){
          float4 a0 = R0[lane];
          float4 a1 = R1[lane];
          #pragma unroll
          for (int c = 0; c < PW; ++c){
            float4 u4 = *(const float4*)&urow[c][lane*4];
            float p0 = panel[r0][c], p1 = panel[r1][c];
            a0.x -= p0*u4.x; a0.y -= p0*u4.y; a0.z -= p0*u4.z; a0.w -= p0*u4.w;
            a1.x -= p1*u4.x; a1.y -= p1*u4.y; a1.z -= p1*u4.z; a1.w -= p1*u4.w;
          }
          R0[lane] = a0;
          R1[lane] = a1;
        }
      }
    }
  }
  __syncthreads();
  if (t < NN) permAll[ls*NN + t] = pivseq[t];
}

// ---------------------------------------------------------------------------
// Kernel 3: blocked triangular solves + epilogue for ONE 64-col RHS chunk.
// Panel rows are STAGED into LDS via coalesced bursts (512 independent
// float4 loads), then consumed as free LDS broadcasts — converts the
// latency-bound wave-uniform L2 reads into a BW-bound coalesced sweep.
// Stage buffer (8 KB) is unioned with epilogue partials to keep 2 blocks/CU.
// ---------------------------------------------------------------------------
__global__ __launch_bounds__(512, 4) void solve_epi_kernel(
    const float* __restrict__ Aall, const int* __restrict__ permAll,
    const float* __restrict__ rowsum,
    const float* __restrict__ C, const float* __restrict__ val,
    const int* __restrict__ bad, const float* __restrict__ rm,
    float* __restrict__ out, int s0)
{
  __shared__ float tile[NN][64];              // 64 KiB
  __shared__ float dblk[PW][PW+1];            // 4.2 KiB
  __shared__ __align__(16) float ubuf[2048];  // 8 KiB: stage (solve) / ep (epilogue)
  __shared__ int   perm[NN];

  int ls, c0;
  {
    const int g = blockIdx.x;
    if ((gridDim.x & 31) == 0){       // cs % 8 == 0: XCD co-location swizzle
      const int xcd = g & 7, idx = g >> 3;
      ls = xcd + 8*(idx >> 2);
      c0 = (idx & 3) * 64;
    } else {
      ls = g >> 2;
      c0 = (g & 3) * 64;
    }
  }
  const int s  = s0 + ls;
  const int k  = s >> 7, b = s & 127;
  const float* __restrict__ A = Aall + (size_t)ls*NN*NN;
  const float* __restrict__ rs = rowsum + ls*NN;
  const int t = threadIdx.x;
  const int lane = t & 63, wid = t >> 6;
  const float sk = sigmoidf_(rm[k]);

  if (t < NN) perm[t] = permAll[ls*NN + t];
  __syncthreads();

  // ---- build permuted RHS chunk on the fly ----
  for (int e = t; e < NN*64; e += 512){
    int i = e >> 6, c = e & 63;
    int pi = perm[i];
    float cb = C[((size_t)b*NN + pi)*(NN+PP) + NN + c0 + c];
    float xb = sk * cb;
    float bf = (1.0f + xb) * expf(-xb);
    if (bad[b*NN + pi]) bf = 0.0f;
    tile[i][c] = bf;
  }
  __syncthreads();

  // ---- forward: y = Linv-chain applied to Pb ----
  for (int J = 0; J < NPAN; ++J){
    const int j0 = J*PW;
    for (int e = t; e < PW*PW; e += 512){
      int r = e >> 5, c = e & 31;
      dblk[r][c] = A[(size_t)perm[j0+r]*NN + j0 + c];
    }
    __syncthreads();
    const int r0 = wid*4;
    float y0 = tile[j0+r0+0][lane];
    float y1 = tile[j0+r0+1][lane];
    float y2 = tile[j0+r0+2][lane];
    float y3 = tile[j0+r0+3][lane];
    for (int kk = 0; kk < r0; ++kk){
      float xk = tile[j0+kk][lane];
      y0 += dblk[r0+0][kk]*xk;
      y1 += dblk[r0+1][kk]*xk;
      y2 += dblk[r0+2][kk]*xk;
      y3 += dblk[r0+3][kk]*xk;
    }
    {
      float x0 = tile[j0+r0][lane], x1 = tile[j0+r0+1][lane], x2 = tile[j0+r0+2][lane];
      y1 += dblk[r0+1][r0]*x0;
      y2 += dblk[r0+2][r0]*x0 + dblk[r0+2][r0+1]*x1;
      y3 += dblk[r0+3][r0]*x0 + dblk[r0+3][r0+1]*x1 + dblk[r0+3][r0+2]*x2;
    }
    __syncthreads();
    tile[j0+r0+0][lane]=y0; tile[j0+r0+1][lane]=y1;
    tile[j0+r0+2][lane]=y2; tile[j0+r0+3][lane]=y3;
    __syncthreads();
    if (j0 + PW < NN){
      float x[PW];
      #pragma unroll
      for (int kk = 0; kk < PW; ++kk) x[kk] = tile[j0+kk][lane];
      const int nbelow = NN - j0 - PW;          // multiple of 32
      for (int cb2 = 0; cb2 < nbelow; cb2 += 64){
        const int rows_c = (nbelow - cb2 < 64) ? (nbelow - cb2) : 64;   // 64 or 32
        // stage rows [j0+PW+cb2, +rows_c) x 32 cols: coalesced, 1 float4/thread
        if (t < rows_c*8){
          int lr = t >> 3, q = t & 7;
          *(float4*)&ubuf[lr*32 + q*4] =
            *(const float4*)(A + (size_t)perm[j0+PW+cb2+lr]*NN + j0 + q*4);
        }
        __syncthreads();
        const int rpw = rows_c >> 3;            // rows per wave: 8 or 4
        for (int p2 = 0; p2 < rpw; p2 += 2){
          const int lr0 = wid*rpw + p2, lr1 = lr0 + 1;
          const int ia = j0 + PW + cb2 + lr0, ib = ia + 1;
          const float4* __restrict__ S0 = (const float4*)&ubuf[lr0*32];
          const float4* __restrict__ S1 = (const float4*)&ubuf[lr1*32];
          float4 A0=S0[0],A1=S0[1],A2=S0[2],A3=S0[3],A4=S0[4],A5=S0[5],A6=S0[6],A7=S0[7];
          float4 B0=S1[0],B1=S1[1],B2=S1[2],B3=S1[3],B4=S1[4],B5=S1[5],B6=S1[6],B7=S1[7];
          float acc0 = tile[ia][lane];
          float acc1 = tile[ib][lane];
          acc0 -= A0.x*x[0]  + A0.y*x[1]  + A0.z*x[2]  + A0.w*x[3];
          acc0 -= A1.x*x[4]  + A1.y*x[5]  + A1.z*x[6]  + A1.w*x[7];
          acc0 -= A2.x*x[8]  + A2.y*x[9]  + A2.z*x[10] + A2.w*x[11];
          acc0 -= A3.x*x[12] + A3.y*x[13] + A3.z*x[14] + A3.w*x[15];
          acc0 -= A4.x*x[16] + A4.y*x[17] + A4.z*x[18] + A4.w*x[19];
          acc0 -= A5.x*x[20] + A5.y*x[21] + A5.z*x[22] + A5.w*x[23];
          acc0 -= A6.x*x[24] + A6.y*x[25] + A6.z*x[26] + A6.w*x[27];
          acc0 -= A7.x*x[28] + A7.y*x[29] + A7.z*x[30] + A7.w*x[31];
          acc1 -= B0.x*x[0]  + B0.y*x[1]  + B0.z*x[2]  + B0.w*x[3];
          acc1 -= B1.x*x[4]  + B1.y*x[5]  + B1.z*x[6]  + B1.w*x[7];
          acc1 -= B2.x*x[8]  + B2.y*x[9]  + B2.z*x[10] + B2.w*x[11];
          acc1 -= B3.x*x[12] + B3.y*x[13] + B3.z*x[14] + B3.w*x[15];
          acc1 -= B4.x*x[16] + B4.y*x[17] + B4.z*x[18] + B4.w*x[19];
          acc1 -= B5.x*x[20] + B5.y*x[21] + B5.z*x[22] + B5.w*x[23];
          acc1 -= B6.x*x[24] + B6.y*x[25] + B6.z*x[26] + B6.w*x[27];
          acc1 -= B7.x*x[28] + B7.y*x[29] + B7.z*x[30] + B7.w*x[31];
          tile[ia][lane] = acc0;
          tile[ib][lane] = acc1;
        }
        __syncthreads();
      }
    } else {
      __syncthreads();   // keep barrier count uniform isn't required; no-op phase
    }
  }

  // ---- backward: d = Uinv-chain applied to y ----
  for (int J = NPAN-1; J >= 0; --J){
    const int j0 = J*PW;
    for (int e = t; e < PW*PW; e += 512){
      int r = e >> 5, c = e & 31;
      dblk[r][c] = A[(size_t)perm[j0+r]*NN + j0 + c];
    }
    __syncthreads();
    const int r0 = wid*4;
    float y0=0.f, y1=0.f, y2=0.f, y3=0.f;
    for (int kk = r0+4; kk < PW; ++kk){
      float xk = tile[j0+kk][lane];
      y0 += dblk[r0+0][kk]*xk;
      y1 += dblk[r0+1][kk]*xk;
      y2 += dblk[r0+2][kk]*xk;
      y3 += dblk[r0+3][kk]*xk;
    }
    {
      float x0 = tile[j0+r0][lane], x1 = tile[j0+r0+1][lane];
      float x2 = tile[j0+r0+2][lane], x3 = tile[j0+r0+3][lane];
      y0 += dblk[r0][r0]*x0 + dblk[r0][r0+1]*x1 + dblk[r0][r0+2]*x2 + dblk[r0][r0+3]*x3;
      y1 += dblk[r0+1][r0+1]*x1 + dblk[r0+1][r0+2]*x2 + dblk[r0+1][r0+3]*x3;
      y2 += dblk[r0+2][r0+2]*x2 + dblk[r0+2][r0+3]*x3;
      y3 += dblk[r0+3][r0+3]*x3;
    }
    __syncthreads();
    tile[j0+r0+0][lane]=y0; tile[j0+r0+1][lane]=y1;
    tile[j0+r0+2][lane]=y2; tile[j0+r0+3][lane]=y3;
    __syncthreads();
    if (j0 > 0){
      float x[PW];
      #pragma unroll
      for (int kk = 0; kk < PW; ++kk) x[kk] = tile[j0+kk][lane];
      for (int cb2 = 0; cb2 < j0; cb2 += 64){
        const int rows_c = (j0 - cb2 < 64) ? (j0 - cb2) : 64;   // 64 or 32
        if (t < rows_c*8){
          int lr = t >> 3, q = t & 7;
          *(float4*)&ubuf[lr*32 + q*4] =
            *(const float4*)(A + (size_t)perm[cb2+lr]*NN + j0 + q*4);
        }
        __syncthreads();
        const int rpw = rows_c >> 3;
        for (int p2 = 0; p2 < rpw; p2 += 2){
          const int lr0 = wid*rpw + p2, lr1 = lr0 + 1;
          const int ia = cb2 + lr0, ib = ia + 1;
          const float4* __restrict__ S0 = (const float4*)&ubuf[lr0*32];
          const float4* __restrict__ S1 = (const float4*)&ubuf[lr1*32];
          float4 A0=S0[0],A1=S0[1],A2=S0[2],A3=S0[3],A4=S0[4],A5=S0[5],A6=S0[6],A7=S0[7];
          float4 B0=S1[0],B1=S1[1],B2=S1[2],B3=S1[3],B4=S1[4],B5=S1[5],B6=S1[6],B7=S1[7];
          float acc0 = tile[ia][lane];
          float acc1 = tile[ib][lane];
          acc0 -= A0.x*x[0]  + A0.y*x[1]  + A0.z*x[2]  + A0.w*x[3];
          acc0 -= A1.x*x[4]  + A1.y*x[5]  + A1.z*x[6]  + A1.w*x[7];
          acc0 -= A2.x*x[8]  + A2.y*x[9]  + A2.z*x[10] + A2.w*x[11];
          acc0 -= A3.x*x[12] + A3.y*x[13] + A3.z*x[14] + A3.w*x[15];
          acc0 -= A4.x*x[16] + A4.y*x[17] + A4.z*x[18] + A4.w*x[19];
          acc0 -= A5.x*x[20] + A5.y*x[21] + A5.z*x[22] + A5.w*x[23];
          acc0 -= A6.x*x[24] + A6.y*x[25] + A6.z*x[26] + A6.w*x[27];
          acc0 -= A7.x*x[28] + A7.y*x[29] + A7.z*x[30] + A7.w*x[31];
          acc1 -= B0.x*x[0]  + B0.y*x[1]  + B0.z*x[2]  + B0.w*x[3];
          acc1 -= B1.x*x[4]  + B1.y*x[5]  + B1.z*x[6]  + B1.w*x[7];
          acc1 -= B2.x*x[8]  + B2.y*x[9]  + B2.z*x[10] + B2.w*x[11];
          acc1 -= B3.x*x[12] + B3.y*x[13] + B3.z*x[14] + B3.w*x[15];
          acc1 -= B4.x*x[16] + B4.y*x[17] + B4.z*x[18] + B4.w*x[19];
          acc1 -= B5.x*x[20] + B5.y*x[21] + B5.z*x[22] + B5.w*x[23];
          acc1 -= B6.x*x[24] + B6.y*x[25] + B6.z*x[26] + B6.w*x[27];
          acc1 -= B7.x*x[28] + B7.y*x[29] + B7.z*x[30] + B7.w*x[31];
          tile[ia][lane] = acc0;
          tile[ib][lane] = acc1;
        }
        __syncthreads();
      }
    }
  }

  // ---- epilogue: 8-wave partial column reductions + combine (ubuf as ep) ----
  {
    const int p = c0 + lane;
    float sdv=0.f, sabs=0.f, s1v=0.f, s1=0.f;
    for (int j = wid*32; j < wid*32 + 32; ++j){
      float d = tile[j][lane];
      float v = val[(b*NN + j)*KK + k];
      if (v != v) v = 0.0f;
      float cb = C[((size_t)b*NN + j)*(NN+PP) + NN + p];
      float xb = sk*cb;
      float bo = (1.0f+xb)*expf(-xb);
      if (bad[b*NN + j]) bo = 0.0f;
      float d1 = bo / rs[j];
      sdv += d*v; sabs += fabsf(d); s1v += d1*v; s1 += d1;
    }
    __syncthreads();   // ubuf (stage) dead; reuse as ep
    ubuf[( 0 + wid)*64 + lane] = sdv;
    ubuf[( 8 + wid)*64 + lane] = sabs;
    ubuf[(16 + wid)*64 + lane] = s1v;
    ubuf[(24 + wid)*64 + lane] = s1;
  }
  __syncthreads();
  if (t < 64){
    float sdv=0.f, sabs=0.f, s1v=0.f, s1=0.f;
    #pragma unroll
    for (int w = 0; w < 8; ++w){
      sdv  += ubuf[( 0 + w)*64 + lane];
      sabs += ubuf[( 8 + w)*64 + lane];
      s1v  += ubuf[(16 + w)*64 + lane];
      s1   += ubuf[(24 + w)*64 + lane];
    }
    float wg    = fminf(fmaxf((sabs - 1.0f)*2.0f, 0.0f), 1.0f);
    float denom = fmaxf(s1, 1.0f);
    out[((size_t)b*PP + c0 + lane)*KK + k] = (1.0f - wg)*sdv + (wg/denom)*s1v;
  }
}

// ---------------------------------------------------------------------------
extern "C" void kernel_launch(void* const* d_in, const int* in_sizes, int n_in,
                              void* d_out, int out_size, void* d_ws, size_t ws_size,
                              hipStream_t stream)
{
  (void)in_sizes; (void)n_in; (void)out_size;
  const float* C    = (const float*)d_in[0];
  const float* val  = (const float*)d_in[1];
  const float* rm   = (const float*)d_in[2];
  const float* epsp = (const float*)d_in[3];
  const int*   bad  = (const int*)d_in[4];
  float* out = (float*)d_out;

  // per-system workspace: A (NN*NN f32) + rowsum (NN f32) + perm (NN i32)
  const size_t per_sys = (size_t)NN*NN*4 + (size_t)NN*4 + (size_t)NN*4;
  int chunk = (int)(ws_size / per_sys);
  if (chunk < 1)    chunk = 1;
  if (chunk > NSYS) chunk = NSYS;

  float* ws     = (float*)d_ws;
  float* A      = ws;
  float* rowsum = A + (size_t)chunk*NN*NN;
  int*   perm   = (int*)(rowsum + (size_t)chunk*NN);

  for (int s0 = 0; s0 < NSYS; s0 += chunk){
    int cs = (NSYS - s0 < chunk) ? (NSYS - s0) : chunk;
    build_kernel<<<cs*NN, 256, 0, stream>>>(C, rm, epsp, bad, A, rowsum, s0);
    lu_kernel<<<cs, 512, 0, stream>>>(A, perm);
    solve_epi_kernel<<<cs*4, 512, 0, stream>>>(A, perm, rowsum, C, val, bad, rm, out, s0);
  }
}

// Round 12
// 1745.372 us; speedup vs baseline: 2.4551x; 2.4551x over previous
//
#include <hip/hip_runtime.h>
#include <cstddef>

#define NN 256      // N
#define PP 256      // P
#define BB 128      // B
#define KK 4        // K
#define NSYS 512    // K*B
#define PW 32       // panel width
#define NPAN (NN/PW)

__device__ __forceinline__ float sigmoidf_(float x){ return 1.0f/(1.0f+expf(-x)); }

// ---------------------------------------------------------------------------
// Kernel 1: build Cm (A) and rowsum(Cm) for systems [s0,s0+cs)
// ---------------------------------------------------------------------------
__global__ __launch_bounds__(256) void build_kernel(
    const float* __restrict__ C, const float* __restrict__ rm,
    const float* __restrict__ epsp, const int* __restrict__ bad,
    float* __restrict__ A, float* __restrict__ rowsum, int s0)
{
  const int si = blockIdx.x;
  const int ls = si >> 8;
  const int i  = si & 255;
  const int s  = s0 + ls;
  const int k  = s >> 7;
  const int b  = s & 127;
  const int j  = threadIdx.x;

  const float sk = sigmoidf_(rm[k]);
  const float ek = sigmoidf_(epsp[k]);
  const bool bad_i = bad[b*NN + i] != 0;
  const bool bad_j = bad[b*NN + j] != 0;

  float c  = C[((size_t)b*NN + i)*(NN+PP) + j];
  float x  = sk * c;
  float cf = (1.0f + x) * expf(-x);
  if (i == j) cf += ek;              // diag: C[i][i]==0 -> cf==1, add eps
  float keep = (bad_i == bad_j) ? 1.0f : 0.0f;
  float a = cf * keep;
  A[((size_t)ls*NN + i)*NN + j] = a;

  __shared__ float red[256];
  red[j] = a; __syncthreads();
  #pragma unroll
  for (int off = 128; off > 0; off >>= 1){
    if (j < off) red[j] += red[j + off];
    __syncthreads();
  }
  if (j == 0) rowsum[ls*NN + i] = red[0];
}

// ---------------------------------------------------------------------------
// Kernel 2: swap-free blocked LU with partial pivoting ("pick-order").
// (round-8 version — measured good: no spill, ~650 us)
// ---------------------------------------------------------------------------
__global__ __launch_bounds__(512, 4) void lu_kernel(
    float* __restrict__ Aall, int* __restrict__ permAll)
{
  __shared__ float panel[NN][PW+1];
  __shared__ float linv[PW][PW+1];
  __shared__ float uinv[PW][PW+1];
  __shared__ float urow[PW][NN-PW];
  __shared__ float redv[2][8];
  __shared__ int   redi[2][8];
  __shared__ int   pivseq[NN];
  __shared__ int   actlist[NN];
  __shared__ unsigned char pickedsh[NN];
  __shared__ int   nact;

  const int ls = blockIdx.x;
  float* __restrict__ A = Aall + (size_t)ls*NN*NN;
  const int t = threadIdx.x;
  const int lane = t & 63, wid = t >> 6;
  bool picked = false;
  if (t < NN) pickedsh[t] = 0;

  for (int I = 0; I < NPAN; ++I){
    const int col0 = I*PW;
    const int W = NN - col0 - PW;
    if (t == 0) nact = 0;
    __syncthreads();

    for (int e = t; e < NN*PW; e += 512){
      int r = e >> 5, c = e & 31;
      panel[r][c] = A[(size_t)r*NN + col0 + c];
    }
    __syncthreads();

    {
      float v = -1.0f; int vi = 0;
      if (t < NN && !picked){ v = fabsf(panel[t][0]); vi = t; }
      #pragma unroll
      for (int off = 32; off > 0; off >>= 1){
        float ov = __shfl_down(v, off); int oi = __shfl_down(vi, off);
        if (ov > v){ v = ov; vi = oi; }
      }
      if (lane == 0){ redv[0][wid] = v; redi[0][wid] = vi; }
    }
    __syncthreads();

    for (int c = 0; c < PW; ++c){
      const int par = c & 1;
      float bv = redv[par][0]; int p = redi[par][0];
      #pragma unroll
      for (int w = 1; w < 8; ++w)
        if (redv[par][w] > bv){ bv = redv[par][w]; p = redi[par][w]; }
      if (t == p){ picked = true; pickedsh[t] = 1; pivseq[col0+c] = t; }

      float nv = -1.0f; int ni = t;
      if (t < NN && !picked){
        const float rdia = 1.0f / panel[p][c];
        float m = panel[t][c] * rdia;
        panel[t][c] = m;
        float nxt = -1.0f;
        #pragma unroll
        for (int j = 0; j < PW; ++j){
          if (j > c){
            float u = panel[t][j] - m * panel[p][j];
            panel[t][j] = u;
            if (j == c+1) nxt = fabsf(u);
          }
        }
        nv = nxt;
      }
      #pragma unroll
      for (int off = 32; off > 0; off >>= 1){
        float ov = __shfl_down(nv, off); int oi = __shfl_down(ni, off);
        if (ov > nv){ nv = ov; ni = oi; }
      }
      if (lane == 0){ redv[par^1][wid] = nv; redi[par^1][wid] = ni; }
      __syncthreads();
    }

    if (t >= 256){
      const int jj = t - 256;
      if (jj < W){
        const int j = col0 + PW + jj;
        float u[PW];
        #pragma unroll
        for (int c = 0; c < PW; ++c) u[c] = A[(size_t)pivseq[col0+c]*NN + j];
        #pragma unroll
        for (int c = 0; c < PW; ++c){
          const int pc = pivseq[col0+c];
          float sv = u[c];
          #pragma unroll
          for (int k2 = 0; k2 < PW; ++k2)
            if (k2 < c) sv -= panel[pc][k2] * u[k2];
          u[c] = sv;
          urow[c][jj] = sv;
          A[(size_t)pc*NN + j] = sv;
        }
      }
    } else if (t < PW){
      const int cth = t;
      for (int r = cth; r < PW; ++r){
        float sv = (r == cth) ? 1.0f : 0.0f;
        const int pr = pivseq[col0+r];
        for (int k2 = cth; k2 < r; ++k2) sv -= panel[pr][k2] * linv[k2][cth];
        linv[r][cth] = sv;
      }
    } else if (t >= 64 && t < 64+PW){
      const int cth = t - 64;
      for (int r = cth; r >= 0; --r){
        float sv = (r == cth) ? 1.0f : 0.0f;
        const int pr = pivseq[col0+r];
        for (int k2 = r+1; k2 <= cth; ++k2) sv -= panel[pr][k2] * uinv[k2][cth];
        uinv[r][cth] = sv / panel[pr][r];
      }
    } else if (t >= 128 && t < 192){
      #pragma unroll
      for (int q = 0; q < 4; ++q){
        int r = (t-128)*4 + q;
        if (!pickedsh[r]){ int pos = atomicAdd(&nact, 1); actlist[pos] = r; }
      }
    }
    __syncthreads();

    for (int e = t; e < PW*PW; e += 512){
      int r = e >> 5, c2 = e & 31;
      A[(size_t)pivseq[col0+r]*NN + col0 + c2] = (r > c2) ? linv[r][c2] : uinv[r][c2];
    }
    for (int e = t; e < NN*PW; e += 512){
      int r = e >> 5, c2 = e & 31;
      if (!pickedsh[r]) A[(size_t)r*NN + col0 + c2] = panel[r][c2];
    }

    if (W > 0){
      for (int i0 = wid*2; i0 < W; i0 += 16){
        const int r0 = actlist[i0];
        const int r1 = actlist[i0+1];          // W even: pair valid
        float4* R0 = (float4*)(A + (size_t)r0*NN + col0 + PW);
        float4* R1 = (float4*)(A + (size_t)r1*NN + col0 + PW);
        if (lane*4 < W){
          float4 a0 = R0[lane];
          float4 a1 = R1[lane];
          #pragma unroll
          for (int c = 0; c < PW; ++c){
            float4 u4 = *(const float4*)&urow[c][lane*4];
            float p0 = panel[r0][c], p1 = panel[r1][c];
            a0.x -= p0*u4.x; a0.y -= p0*u4.y; a0.z -= p0*u4.z; a0.w -= p0*u4.w;
            a1.x -= p1*u4.x; a1.y -= p1*u4.y; a1.z -= p1*u4.z; a1.w -= p1*u4.w;
          }
          R0[lane] = a0;
          R1[lane] = a1;
        }
      }
    }
  }
  __syncthreads();
  if (t < NN) permAll[ls*NN + t] = pivseq[t];
}

// ---------------------------------------------------------------------------
// Kernel 3: blocked triangular solves + epilogue for ONE 64-col RHS chunk.
// Panel rows staged to LDS via coalesced bursts; consumed WITHOUT hoisting
// (2 float4 LDS reads per FMA step) to keep register pressure ~50 VGPRs.
// __launch_bounds__(512) only — LDS caps occupancy at 2 blocks/CU; no
// min-waves hint so the allocator isn't pinned to 64 VGPRs (round-11 spill).
// ---------------------------------------------------------------------------
__global__ __launch_bounds__(512) void solve_epi_kernel(
    const float* __restrict__ Aall, const int* __restrict__ permAll,
    const float* __restrict__ rowsum,
    const float* __restrict__ C, const float* __restrict__ val,
    const int* __restrict__ bad, const float* __restrict__ rm,
    float* __restrict__ out, int s0)
{
  __shared__ float tile[NN][64];              // 64 KiB
  __shared__ float dblk[PW][PW+1];            // 4.2 KiB
  __shared__ __align__(16) float ubuf[2048];  // 8 KiB: stage (solve) / ep (epilogue)
  __shared__ int   perm[NN];

  int ls, c0;
  {
    const int g = blockIdx.x;
    if ((gridDim.x & 31) == 0){       // cs % 8 == 0: XCD co-location swizzle
      const int xcd = g & 7, idx = g >> 3;
      ls = xcd + 8*(idx >> 2);
      c0 = (idx & 3) * 64;
    } else {
      ls = g >> 2;
      c0 = (g & 3) * 64;
    }
  }
  const int s  = s0 + ls;
  const int k  = s >> 7, b = s & 127;
  const float* __restrict__ A = Aall + (size_t)ls*NN*NN;
  const float* __restrict__ rs = rowsum + ls*NN;
  const int t = threadIdx.x;
  const int lane = t & 63, wid = t >> 6;
  const float sk = sigmoidf_(rm[k]);

  if (t < NN) perm[t] = permAll[ls*NN + t];
  __syncthreads();

  // ---- build permuted RHS chunk on the fly ----
  for (int e = t; e < NN*64; e += 512){
    int i = e >> 6, c = e & 63;
    int pi = perm[i];
    float cb = C[((size_t)b*NN + pi)*(NN+PP) + NN + c0 + c];
    float xb = sk * cb;
    float bf = (1.0f + xb) * expf(-xb);
    if (bad[b*NN + pi]) bf = 0.0f;
    tile[i][c] = bf;
  }
  __syncthreads();

  // ---- forward: y = Linv-chain applied to Pb ----
  for (int J = 0; J < NPAN; ++J){
    const int j0 = J*PW;
    for (int e = t; e < PW*PW; e += 512){
      int r = e >> 5, c = e & 31;
      dblk[r][c] = A[(size_t)perm[j0+r]*NN + j0 + c];
    }
    __syncthreads();
    const int r0 = wid*4;
    float y0 = tile[j0+r0+0][lane];
    float y1 = tile[j0+r0+1][lane];
    float y2 = tile[j0+r0+2][lane];
    float y3 = tile[j0+r0+3][lane];
    for (int kk = 0; kk < r0; ++kk){
      float xk = tile[j0+kk][lane];
      y0 += dblk[r0+0][kk]*xk;
      y1 += dblk[r0+1][kk]*xk;
      y2 += dblk[r0+2][kk]*xk;
      y3 += dblk[r0+3][kk]*xk;
    }
    {
      float x0 = tile[j0+r0][lane], x1 = tile[j0+r0+1][lane], x2 = tile[j0+r0+2][lane];
      y1 += dblk[r0+1][r0]*x0;
      y2 += dblk[r0+2][r0]*x0 + dblk[r0+2][r0+1]*x1;
      y3 += dblk[r0+3][r0]*x0 + dblk[r0+3][r0+1]*x1 + dblk[r0+3][r0+2]*x2;
    }
    __syncthreads();
    tile[j0+r0+0][lane]=y0; tile[j0+r0+1][lane]=y1;
    tile[j0+r0+2][lane]=y2; tile[j0+r0+3][lane]=y3;
    __syncthreads();
    if (j0 + PW < NN){
      float x[PW];
      #pragma unroll
      for (int kk = 0; kk < PW; ++kk) x[kk] = tile[j0+kk][lane];
      const int nbelow = NN - j0 - PW;          // multiple of 32
      for (int cb2 = 0; cb2 < nbelow; cb2 += 64){
        const int rows_c = (nbelow - cb2 < 64) ? (nbelow - cb2) : 64;   // 64 or 32
        if (t < rows_c*8){
          int lr = t >> 3, q = t & 7;
          *(float4*)&ubuf[(lr<<5) + (q<<2)] =
            *(const float4*)(A + (size_t)perm[j0+PW+cb2+lr]*NN + j0 + (q<<2));
        }
        __syncthreads();
        const int rpw = rows_c >> 3;            // rows per wave: 8 or 4
        for (int p2 = 0; p2 < rpw; p2 += 2){
          const int lr0 = wid*rpw + p2;
          const int ia = j0 + PW + cb2 + lr0, ib = ia + 1;
          const float* __restrict__ S0 = &ubuf[lr0<<5];
          const float* __restrict__ S1 = &ubuf[(lr0+1)<<5];
          float acc0 = tile[ia][lane];
          float acc1 = tile[ib][lane];
          #pragma unroll
          for (int q = 0; q < 8; ++q){
            float4 a4 = *(const float4*)(S0 + (q<<2));
            float4 b4 = *(const float4*)(S1 + (q<<2));
            acc0 -= a4.x*x[q*4+0] + a4.y*x[q*4+1] + a4.z*x[q*4+2] + a4.w*x[q*4+3];
            acc1 -= b4.x*x[q*4+0] + b4.y*x[q*4+1] + b4.z*x[q*4+2] + b4.w*x[q*4+3];
          }
          tile[ia][lane] = acc0;
          tile[ib][lane] = acc1;
        }
        __syncthreads();
      }
    }
  }

  // ---- backward: d = Uinv-chain applied to y ----
  for (int J = NPAN-1; J >= 0; --J){
    const int j0 = J*PW;
    for (int e = t; e < PW*PW; e += 512){
      int r = e >> 5, c = e & 31;
      dblk[r][c] = A[(size_t)perm[j0+r]*NN + j0 + c];
    }
    __syncthreads();
    const int r0 = wid*4;
    float y0=0.f, y1=0.f, y2=0.f, y3=0.f;
    for (int kk = r0+4; kk < PW; ++kk){
      float xk = tile[j0+kk][lane];
      y0 += dblk[r0+0][kk]*xk;
      y1 += dblk[r0+1][kk]*xk;
      y2 += dblk[r0+2][kk]*xk;
      y3 += dblk[r0+3][kk]*xk;
    }
    {
      float x0 = tile[j0+r0][lane], x1 = tile[j0+r0+1][lane];
      float x2 = tile[j0+r0+2][lane], x3 = tile[j0+r0+3][lane];
      y0 += dblk[r0][r0]*x0 + dblk[r0][r0+1]*x1 + dblk[r0][r0+2]*x2 + dblk[r0][r0+3]*x3;
      y1 += dblk[r0+1][r0+1]*x1 + dblk[r0+1][r0+2]*x2 + dblk[r0+1][r0+3]*x3;
      y2 += dblk[r0+2][r0+2]*x2 + dblk[r0+2][r0+3]*x3;
      y3 += dblk[r0+3][r0+3]*x3;
    }
    __syncthreads();
    tile[j0+r0+0][lane]=y0; tile[j0+r0+1][lane]=y1;
    tile[j0+r0+2][lane]=y2; tile[j0+r0+3][lane]=y3;
    __syncthreads();
    if (j0 > 0){
      float x[PW];
      #pragma unroll
      for (int kk = 0; kk < PW; ++kk) x[kk] = tile[j0+kk][lane];
      for (int cb2 = 0; cb2 < j0; cb2 += 64){
        const int rows_c = (j0 - cb2 < 64) ? (j0 - cb2) : 64;   // 64 or 32
        if (t < rows_c*8){
          int lr = t >> 3, q = t & 7;
          *(float4*)&ubuf[(lr<<5) + (q<<2)] =
            *(const float4*)(A + (size_t)perm[cb2+lr]*NN + j0 + (q<<2));
        }
        __syncthreads();
        const int rpw = rows_c >> 3;
        for (int p2 = 0; p2 < rpw; p2 += 2){
          const int lr0 = wid*rpw + p2;
          const int ia = cb2 + lr0, ib = ia + 1;
          const float* __restrict__ S0 = &ubuf[lr0<<5];
          const float* __restrict__ S1 = &ubuf[(lr0+1)<<5];
          float acc0 = tile[ia][lane];
          float acc1 = tile[ib][lane];
          #pragma unroll
          for (int q = 0; q < 8; ++q){
            float4 a4 = *(const float4*)(S0 + (q<<2));
            float4 b4 = *(const float4*)(S1 + (q<<2));
            acc0 -= a4.x*x[q*4+0] + a4.y*x[q*4+1] + a4.z*x[q*4+2] + a4.w*x[q*4+3];
            acc1 -= b4.x*x[q*4+0] + b4.y*x[q*4+1] + b4.z*x[q*4+2] + b4.w*x[q*4+3];
          }
          tile[ia][lane] = acc0;
          tile[ib][lane] = acc1;
        }
        __syncthreads();
      }
    }
  }

  // ---- epilogue: 8-wave partial column reductions + combine (ubuf as ep) ----
  {
    const int p = c0 + lane;
    float sdv=0.f, sabs=0.f, s1v=0.f, s1=0.f;
    for (int j = wid*32; j < wid*32 + 32; ++j){
      float d = tile[j][lane];
      float v = val[(b*NN + j)*KK + k];
      if (v != v) v = 0.0f;
      float cb = C[((size_t)b*NN + j)*(NN+PP) + NN + p];
      float xb = sk*cb;
      float bo = (1.0f+xb)*expf(-xb);
      if (bad[b*NN + j]) bo = 0.0f;
      float d1 = bo / rs[j];
      sdv += d*v; sabs += fabsf(d); s1v += d1*v; s1 += d1;
    }
    __syncthreads();   // ubuf (stage) dead; reuse as ep
    ubuf[( 0 + wid)*64 + lane] = sdv;
    ubuf[( 8 + wid)*64 + lane] = sabs;
    ubuf[(16 + wid)*64 + lane] = s1v;
    ubuf[(24 + wid)*64 + lane] = s1;
  }
  __syncthreads();
  if (t < 64){
    float sdv=0.f, sabs=0.f, s1v=0.f, s1=0.f;
    #pragma unroll
    for (int w = 0; w < 8; ++w){
      sdv  += ubuf[( 0 + w)*64 + lane];
      sabs += ubuf[( 8 + w)*64 + lane];
      s1v  += ubuf[(16 + w)*64 + lane];
      s1   += ubuf[(24 + w)*64 + lane];
    }
    float wg    = fminf(fmaxf((sabs - 1.0f)*2.0f, 0.0f), 1.0f);
    float denom = fmaxf(s1, 1.0f);
    out[((size_t)b*PP + c0 + lane)*KK + k] = (1.0f - wg)*sdv + (wg/denom)*s1v;
  }
}

// ---------------------------------------------------------------------------
extern "C" void kernel_launch(void* const* d_in, const int* in_sizes, int n_in,
                              void* d_out, int out_size, void* d_ws, size_t ws_size,
                              hipStream_t stream)
{
  (void)in_sizes; (void)n_in; (void)out_size;
  const float* C    = (const float*)d_in[0];
  const float* val  = (const float*)d_in[1];
  const float* rm   = (const float*)d_in[2];
  const float* epsp = (const float*)d_in[3];
  const int*   bad  = (const int*)d_in[4];
  float* out = (float*)d_out;

  // per-system workspace: A (NN*NN f32) + rowsum (NN f32) + perm (NN i32)
  const size_t per_sys = (size_t)NN*NN*4 + (size_t)NN*4 + (size_t)NN*4;
  int chunk = (int)(ws_size / per_sys);
  if (chunk < 1)    chunk = 1;
  if (chunk > NSYS) chunk = NSYS;

  float* ws     = (float*)d_ws;
  float* A      = ws;
  float* rowsum = A + (size_t)chunk*NN*NN;
  int*   perm   = (int*)(rowsum + (size_t)chunk*NN);

  for (int s0 = 0; s0 < NSYS; s0 += chunk){
    int cs = (NSYS - s0 < chunk) ? (NSYS - s0) : chunk;
    build_kernel<<<cs*NN, 256, 0, stream>>>(C, rm, epsp, bad, A, rowsum, s0);
    lu_kernel<<<cs, 512, 0, stream>>>(A, perm);
    solve_epi_kernel<<<cs*4, 512, 0, stream>>>(A, perm, rowsum, C, val, bad, rm, out, s0);
  }
}